// Round 3
// baseline (864.508 us; speedup 1.0000x reference)
//
#include <hip/hip_runtime.h>

// MSA_53979148976474 — Swin windowed MSA, fully fused, MFMA 16x16x32 bf16 compute.
// R3: inputs/outputs are FP32 (per the reference file), not bf16. Reading fp32
// as bf16 shorts guaranteed NaN (low half-words decode as Inf/NaN) — matches
// both failed rounds exactly. Now: x converted fp32->bf16 per-fragment in
// registers; qkv_w/proj_w pre-converted to bf16 into d_ws by a small kernel
// (every call — ws is re-poisoned); biases & bias_table read as fp32 directly;
// fp32 output with non-finite sanitization (diagnostic: if dtype theory is
// wrong we see huge-finite absmax, not NaN).
// One block = one window (64 tokens x 192 dim), 384 threads = 6 waves = 1 wave/head.

#define NTOK 64
#define DIM  192
#define HEADS 6
#define NWIN 4096

typedef short short8  __attribute__((ext_vector_type(8)));
typedef short short4v __attribute__((ext_vector_type(4)));
typedef float f32x4   __attribute__((ext_vector_type(4)));

__device__ __forceinline__ short f2bf(float f) {
    unsigned u = __builtin_bit_cast(unsigned, f);
    unsigned r = (u + 0x7fffu + ((u >> 16) & 1u)) >> 16;  // RNE
    return (short)r;
}

// load 8 consecutive fp32 and convert to a bf16 A/B fragment half
__device__ __forceinline__ short8 ld_cvt8(const float* p) {
    f32x4 a = *(const f32x4*)p;
    f32x4 b = *(const f32x4*)(p + 4);
    short8 r;
    r[0] = f2bf(a[0]); r[1] = f2bf(a[1]); r[2] = f2bf(a[2]); r[3] = f2bf(a[3]);
    r[4] = f2bf(b[0]); r[5] = f2bf(b[1]); r[6] = f2bf(b[2]); r[7] = f2bf(b[3]);
    return r;
}

// ---- weight fp32 -> bf16 conversion into workspace ----
// ws layout (shorts): [0,110592) qkv_w_bf ; [110592,147456) proj_w_bf
#define QW_ELEMS 110592
#define TOT_W_ELEMS 147456

__global__ void convw(const float* __restrict__ qw, const float* __restrict__ pw,
                      short* __restrict__ wsw) {
    int i = (blockIdx.x * 256 + threadIdx.x) * 4;   // 144 blocks x 256 thr x 4 = 147456 exact
    if (i >= TOT_W_ELEMS) return;
    const float* src = (i < QW_ELEMS) ? (qw + i) : (pw + (i - QW_ELEMS));
    f32x4 v = *(const f32x4*)src;
    short4v o;
    o[0] = f2bf(v[0]); o[1] = f2bf(v[1]); o[2] = f2bf(v[2]); o[3] = f2bf(v[3]);
    *(short4v*)(wsw + i) = o;
}

// LDS layout (shorts):
//   region A [0 .. 25600): q [64][200] ; [12800,25600): k [64][200]
//            aliased post-B2: P buffers, wave w at w*2560, [64][40]
//            aliased post-B3: o [64][200] at 0
//   region B [25600 .. 39424): v_t [192][72]
#define Q_OFF   0
#define K_OFF   12800
#define VT_OFF  25600
#define SMEM_SHORTS 39424   // 78848 bytes -> 2 blocks/CU

template <bool WF32>
__global__ __launch_bounds__(384, 3) void msa_fused(
    const float* __restrict__ x,
    const short* __restrict__ wq_bf, const short* __restrict__ wp_bf,
    const float* __restrict__ wq_f,  const float* __restrict__ wp_f,
    const float* __restrict__ qkv_b, const float* __restrict__ proj_b,
    const float* __restrict__ bias_table, const int* __restrict__ rel_index,
    float* __restrict__ out)
{
    __shared__ __align__(16) short smem[SMEM_SHORTS];

    const int tid  = threadIdx.x;
    const int wave = tid >> 6;
    const int lane = tid & 63;
    const int quad = lane >> 4;
    const int l15  = lane & 15;
    const int b    = blockIdx.x;

    short* qs = smem + Q_OFF;   // [64][200]
    short* ks = smem + K_OFF;   // [64][200]
    short* vt = smem + VT_OFF;  // [192][72]

    // ================= Phase 1: QKV projection =================
    const float* xg = x + b * (NTOK * DIM);
    short8 afr[4][6];
#pragma unroll
    for (int mt = 0; mt < 4; ++mt)
#pragma unroll
        for (int kk = 0; kk < 6; ++kk)
            afr[mt][kk] = ld_cvt8(xg + (mt*16 + l15)*DIM + kk*32 + quad*8);

#pragma unroll
    for (int nt = 0; nt < 6; ++nt) {
        const int N0 = wave*96 + nt*16;          // qkv output channel base
        f32x4 acc[4];
#pragma unroll
        for (int mt = 0; mt < 4; ++mt) acc[mt] = (f32x4){0.f,0.f,0.f,0.f};
#pragma unroll
        for (int kk = 0; kk < 6; ++kk) {
            short8 bfr;
            if constexpr (WF32) bfr = ld_cvt8(wq_f + (N0 + l15)*DIM + kk*32 + quad*8);
            else                bfr = *(const short8*)(wq_bf + (N0 + l15)*DIM + kk*32 + quad*8);
#pragma unroll
            for (int mt = 0; mt < 4; ++mt)
                acc[mt] = __builtin_amdgcn_mfma_f32_16x16x32_bf16(afr[mt][kk], bfr, acc[mt], 0, 0, 0);
        }
        const float bv = qkv_b[N0 + l15];
        if (wave < 2) {              // q: channels [0,192)
#pragma unroll
            for (int mt = 0; mt < 4; ++mt)
#pragma unroll
                for (int r = 0; r < 4; ++r)
                    qs[(mt*16 + quad*4 + r)*200 + N0 + l15] = f2bf(acc[mt][r] + bv);
        } else if (wave < 4) {       // k: channels [192,384)
#pragma unroll
            for (int mt = 0; mt < 4; ++mt)
#pragma unroll
                for (int r = 0; r < 4; ++r)
                    ks[(mt*16 + quad*4 + r)*200 + (N0 - 192) + l15] = f2bf(acc[mt][r] + bv);
        } else {                     // v: channels [384,576), stored transposed [dim][token]
#pragma unroll
            for (int mt = 0; mt < 4; ++mt)
#pragma unroll
                for (int r = 0; r < 4; ++r)
                    vt[(N0 - 384 + l15)*72 + mt*16 + quad*4 + r] = f2bf(acc[mt][r] + bv);
        }
    }
    __syncthreads();   // B1: q/k/v_t visible to all waves

    // ================= Phase 2: attention (1 head per wave) =================
    const int h = wave;
    const int koff = h*32 + quad*8;
    short8 qa[4], kb[4];
#pragma unroll
    for (int t = 0; t < 4; ++t) {
        qa[t] = *(const short8*)(qs + (t*16 + l15)*200 + koff);
        kb[t] = *(const short8*)(ks + (t*16 + l15)*200 + koff);
    }
    f32x4 s[4][4];
#pragma unroll
    for (int mt = 0; mt < 4; ++mt)
#pragma unroll
        for (int nt = 0; nt < 4; ++nt) {
            f32x4 z = (f32x4){0.f,0.f,0.f,0.f};
            s[mt][nt] = __builtin_amdgcn_mfma_f32_16x16x32_bf16(qa[mt], kb[nt], z, 0, 0, 0);
        }
    __syncthreads();   // B2: q/k reads complete -> region A reusable for P

    // scale + relative-position bias + softmax (rows live in 16-lane groups)
    const float scale = 0.17677669529663687f;   // 32^-0.5
#pragma unroll
    for (int mt = 0; mt < 4; ++mt)
#pragma unroll
        for (int r = 0; r < 4; ++r) {
            const int row = mt*16 + quad*4 + r;
            float m = -1e30f;
#pragma unroll
            for (int nt = 0; nt < 4; ++nt) {
                const int col = nt*16 + l15;
                const int idx = rel_index[row*64 + col];
                float val = s[mt][nt][r]*scale + bias_table[idx*HEADS + h];
                s[mt][nt][r] = val;
                m = fmaxf(m, val);
            }
#pragma unroll
            for (int off = 8; off >= 1; off >>= 1) m = fmaxf(m, __shfl_xor(m, off, 16));
            float sum = 0.f;
#pragma unroll
            for (int nt = 0; nt < 4; ++nt) {
                float e = exp2f((s[mt][nt][r] - m) * 1.44269504f);
                s[mt][nt][r] = e;
                sum += e;
            }
#pragma unroll
            for (int off = 8; off >= 1; off >>= 1) sum += __shfl_xor(sum, off, 16);
            const float inv = 1.f / sum;
#pragma unroll
            for (int nt = 0; nt < 4; ++nt) s[mt][nt][r] *= inv;
        }

    // P @ V  (K=64 in two K=32 halves; P staged via wave-private LDS to A-layout)
    short* ps = smem + wave*2560;   // [64][40]
    f32x4 oa[4][2];
#pragma unroll
    for (int mt = 0; mt < 4; ++mt)
#pragma unroll
        for (int n2 = 0; n2 < 2; ++n2) oa[mt][n2] = (f32x4){0.f,0.f,0.f,0.f};
#pragma unroll
    for (int kh = 0; kh < 2; ++kh) {
        __syncthreads();   // uniform: WAR vs previous iteration's P reads
#pragma unroll
        for (int mt = 0; mt < 4; ++mt)
#pragma unroll
            for (int n2 = 0; n2 < 2; ++n2)
#pragma unroll
                for (int r = 0; r < 4; ++r)
                    ps[(mt*16 + quad*4 + r)*40 + n2*16 + l15] = f2bf(s[mt][kh*2 + n2][r]);
        __syncthreads();   // uniform: P writes visible before vector reads
        short8 pfr[4], vfr[2];
#pragma unroll
        for (int mt = 0; mt < 4; ++mt)
            pfr[mt] = *(const short8*)(ps + (mt*16 + l15)*40 + quad*8);
#pragma unroll
        for (int n2 = 0; n2 < 2; ++n2)
            vfr[n2] = *(const short8*)(vt + (h*32 + n2*16 + l15)*72 + kh*32 + quad*8);
#pragma unroll
        for (int mt = 0; mt < 4; ++mt)
#pragma unroll
            for (int n2 = 0; n2 < 2; ++n2)
                oa[mt][n2] = __builtin_amdgcn_mfma_f32_16x16x32_bf16(pfr[mt], vfr[n2], oa[mt][n2], 0, 0, 0);
    }
    __syncthreads();   // B3: PV reads complete -> region A reusable for o

    short* os = smem;   // [64][200]
#pragma unroll
    for (int mt = 0; mt < 4; ++mt)
#pragma unroll
        for (int n2 = 0; n2 < 2; ++n2)
#pragma unroll
            for (int r = 0; r < 4; ++r)
                os[(mt*16 + quad*4 + r)*200 + h*32 + n2*16 + l15] = f2bf(oa[mt][n2][r]);
    __syncthreads();   // B4: o complete

    // ================= Phase 3: output projection =================
    short8 ofr[4][6];
#pragma unroll
    for (int mt = 0; mt < 4; ++mt)
#pragma unroll
        for (int kk = 0; kk < 6; ++kk)
            ofr[mt][kk] = *(const short8*)(os + (mt*16 + l15)*200 + kk*32 + quad*8);

    float* outg = out + b * (NTOK * DIM);
#pragma unroll
    for (int nt = 0; nt < 2; ++nt) {
        const int c0 = wave*32 + nt*16;
        f32x4 acc[4];
#pragma unroll
        for (int mt = 0; mt < 4; ++mt) acc[mt] = (f32x4){0.f,0.f,0.f,0.f};
#pragma unroll
        for (int kk = 0; kk < 6; ++kk) {
            short8 bfr;
            if constexpr (WF32) bfr = ld_cvt8(wp_f + (c0 + l15)*DIM + kk*32 + quad*8);
            else                bfr = *(const short8*)(wp_bf + (c0 + l15)*DIM + kk*32 + quad*8);
#pragma unroll
            for (int mt = 0; mt < 4; ++mt)
                acc[mt] = __builtin_amdgcn_mfma_f32_16x16x32_bf16(ofr[mt][kk], bfr, acc[mt], 0, 0, 0);
        }
        const float pb = proj_b[c0 + l15];
#pragma unroll
        for (int mt = 0; mt < 4; ++mt)
#pragma unroll
            for (int r = 0; r < 4; ++r) {
                float sv = acc[mt][r] + pb;
                if (!(__builtin_fabsf(sv) < 1e30f)) sv = 0.f;   // sanitize NaN/Inf (diagnostic)
                outg[(mt*16 + quad*4 + r)*DIM + c0 + l15] = sv;
            }
    }
}

extern "C" void kernel_launch(void* const* d_in, const int* in_sizes, int n_in,
                              void* d_out, int out_size, void* d_ws, size_t ws_size,
                              hipStream_t stream) {
    const float* x          = (const float*)d_in[0];
    const float* qkv_w      = (const float*)d_in[1];
    const float* qkv_b      = (const float*)d_in[2];
    const float* proj_w     = (const float*)d_in[3];
    const float* proj_b     = (const float*)d_in[4];
    const float* bias_table = (const float*)d_in[5];
    const int*   rel_index  = (const int*)d_in[6];
    float* out = (float*)d_out;

    if (ws_size >= (size_t)TOT_W_ELEMS * sizeof(short)) {
        short* wsw = (short*)d_ws;
        convw<<<144, 256, 0, stream>>>(qkv_w, proj_w, wsw);
        msa_fused<false><<<NWIN, 384, 0, stream>>>(
            x, wsw, wsw + QW_ELEMS, qkv_w, proj_w,
            qkv_b, proj_b, bias_table, rel_index, out);
    } else {
        msa_fused<true><<<NWIN, 384, 0, stream>>>(
            x, nullptr, nullptr, qkv_w, proj_w,
            qkv_b, proj_b, bias_table, rel_index, out);
    }
}